// Round 12
// baseline (291.061 us; speedup 1.0000x reference)
//
#include <hip/hip_runtime.h>
#include <math.h>

#define NN 768
#define DD 128
#define AA 312
#define HH 8
#define CEPS 1e-8f

typedef __attribute__((ext_vector_type(8))) short s8b;   // 8 x bf16
typedef __attribute__((ext_vector_type(4))) float f4v;   // MFMA C/D

__device__ __forceinline__ float wave_sum(float v) {
    #pragma unroll
    for (int o = 32; o; o >>= 1) v += __shfl_down(v, o, 64);
    return v;
}
__device__ __forceinline__ float wave_max(float v) {
    #pragma unroll
    for (int o = 32; o; o >>= 1) v = fmaxf(v, __shfl_down(v, o, 64));
    return v;
}
__device__ __forceinline__ unsigned short f2bf(float f) {
    unsigned u = __float_as_uint(f);
    u += 0x7FFFu + ((u >> 16) & 1u);
    return (unsigned short)(u >> 16);
}

struct KParams {
    const float *visual, *semantic, *attribute;
    const float *Wvn, *bvn, *gvn, *betavn, *Wve1, *bve1, *Wve2, *bve2;
    const float *Wsn, *bsn, *gsn, *betasn, *Wse1, *bse1, *Wse2, *bse2;
    float *vp, *sp, *ve2, *se2;
    float *simv, *sima, *WvnT, *WsnT, *cvec1, *cvec2;
    float *nrmv, *nrma, *ve, *se;
    float *pagg1, *xagg1, *pagg2, *xagg2;
    short *vpb, *spb, *visbT, *sembT;
    short *veh, *vel, *seh, *sel, *ve2h, *ve2l;
};

// ---------------- K1: MFMA bf16x2-split gram + norms + W transposes + bf16-T copies --------
__global__ __launch_bounds__(256) void gram_mfma_kernel(KParams p) {
    __shared__ __align__(16) unsigned short AH[64 * 40];
    __shared__ __align__(16) unsigned short AL[64 * 40];
    __shared__ __align__(16) unsigned short BH[64 * 40];
    __shared__ __align__(16) unsigned short BL[64 * 40];
    const int task = blockIdx.x;
    const int tid = threadIdx.x;
    if (task < 288) {
        const bool isv = (task < 144);
        const int tt = isv ? task : task - 144;
        const int bi = tt / 12, bj = tt % 12;
        const float* M = isv ? p.visual : p.attribute;
        float* G = isv ? p.simv : p.sima;
        float* nrm = isv ? p.nrmv : p.nrma;
        const int K = isv ? DD : AA;
        const int i0 = bi * 64, j0 = bj * 64;
        const int w = tid >> 6, lane = tid & 63;
        const int m = lane & 15, q = lane >> 4;
        f4v acc[4] = {{0.f, 0.f, 0.f, 0.f}, {0.f, 0.f, 0.f, 0.f},
                      {0.f, 0.f, 0.f, 0.f}, {0.f, 0.f, 0.f, 0.f}};
        const int nchunk = (K + 31) >> 5;
        const int srow = tid >> 2, sq = (tid & 3) * 8;
        for (int c = 0; c < nchunk; ++c) {
            const int kc = c * 32;
            __syncthreads();
            #pragma unroll
            for (int h = 0; h < 2; ++h) {
                const int col = sq + h * 4;
                float4 a = {0.f, 0.f, 0.f, 0.f}, b = {0.f, 0.f, 0.f, 0.f};
                if (kc + col + 4 <= K) {
                    a = *(const float4*)(M + (size_t)(i0 + srow) * K + kc + col);
                    b = *(const float4*)(M + (size_t)(j0 + srow) * K + kc + col);
                }
                const float av[4] = {a.x, a.y, a.z, a.w};
                const float bv[4] = {b.x, b.y, b.z, b.w};
                #pragma unroll
                for (int e = 0; e < 4; ++e) {
                    const unsigned short ah = f2bf(av[e]);
                    const float ahf = __uint_as_float((unsigned)ah << 16);
                    const unsigned short al = f2bf(av[e] - ahf);
                    const unsigned short bh = f2bf(bv[e]);
                    const float bhf = __uint_as_float((unsigned)bh << 16);
                    const unsigned short bl = f2bf(bv[e] - bhf);
                    AH[srow * 40 + col + e] = ah;
                    AL[srow * 40 + col + e] = al;
                    BH[srow * 40 + col + e] = bh;
                    BL[srow * 40 + col + e] = bl;
                }
            }
            __syncthreads();
            const s8b ah8 = *(const s8b*)&AH[(w * 16 + m) * 40 + q * 8];
            const s8b al8 = *(const s8b*)&AL[(w * 16 + m) * 40 + q * 8];
            #pragma unroll
            for (int jt = 0; jt < 4; ++jt) {
                const s8b bh8 = *(const s8b*)&BH[(jt * 16 + m) * 40 + q * 8];
                const s8b bl8 = *(const s8b*)&BL[(jt * 16 + m) * 40 + q * 8];
                acc[jt] = __builtin_amdgcn_mfma_f32_16x16x32_bf16(ah8, bh8, acc[jt], 0, 0, 0);
                acc[jt] = __builtin_amdgcn_mfma_f32_16x16x32_bf16(ah8, bl8, acc[jt], 0, 0, 0);
                acc[jt] = __builtin_amdgcn_mfma_f32_16x16x32_bf16(al8, bh8, acc[jt], 0, 0, 0);
            }
        }
        #pragma unroll
        for (int jt = 0; jt < 4; ++jt) {
            #pragma unroll
            for (int r = 0; r < 4; ++r) {
                G[(size_t)(i0 + w * 16 + q * 4 + r) * NN + j0 + jt * 16 + m] = acc[jt][r];
                if (bi == bj && jt == w && m == q * 4 + r)
                    nrm[i0 + w * 16 + m] = sqrtf(fmaxf(acc[jt][r], 0.f));
            }
        }
    } else if (task < 320) {
        float* smem = (float*)AH;
        const int u = task - 288;
        const float* S = (u >= 16) ? p.Wsn : p.Wvn;
        float* Dt = (u >= 16) ? p.WsnT : p.WvnT;
        const int tile = u & 15;
        const int c0 = (tile & 3) * 32, r0 = (tile >> 2) * 32;
        const int tx = tid & 31, ty = tid >> 5;
        #pragma unroll
        for (int rr = ty; rr < 32; rr += 8)
            smem[rr * 33 + tx] = S[(size_t)(r0 + rr) * DD + c0 + tx];
        __syncthreads();
        #pragma unroll
        for (int rr = ty; rr < 32; rr += 8)
            Dt[(size_t)(c0 + rr) * DD + r0 + tx] = smem[tx * 33 + rr];
    } else {
        // transposed bf16 copies: visbT/sembT [128][768] (tasks 320-331 / 332-343)
        const int u = task - 320;
        const bool isv = (u < 12);
        const float* src = isv ? p.visual : p.semantic;
        short* dst = isv ? p.visbT : p.sembT;
        const int r0 = (isv ? u : u - 12) * 64;
        for (int e = tid * 4; e < 8192; e += 1024) {
            const int r = r0 + (e >> 7);
            const int c = e & 127;
            const float4 v = *(const float4*)(src + (size_t)r * DD + c);
            dst[(size_t)(c + 0) * NN + r] = (short)f2bf(v.x);
            dst[(size_t)(c + 1) * NN + r] = (short)f2bf(v.y);
            dst[(size_t)(c + 2) * NN + r] = (short)f2bf(v.z);
            dst[(size_t)(c + 3) * NN + r] = (short)f2bf(v.w);
        }
    }
}

// Two concurrent 768-float softmaxes: waves 0-3 on A, waves 4-7 on B. 3 barriers.
__device__ void softmax768_pair(float* A, float* B, int tid, float* red) {
    float* buf = (tid < 256) ? A : B;
    const int st = tid & 255;
    const int g = tid >> 8;
    const int w4 = (tid >> 6) & 3;
    float v0 = buf[st], v1 = buf[st + 256], v2 = buf[st + 512];
    float m = wave_max(fmaxf(fmaxf(v0, v1), v2));
    if ((tid & 63) == 0) red[g * 8 + w4] = m;
    __syncthreads();
    m = fmaxf(fmaxf(red[g * 8], red[g * 8 + 1]), fmaxf(red[g * 8 + 2], red[g * 8 + 3]));
    float e0 = __expf(v0 - m), e1 = __expf(v1 - m), e2 = __expf(v2 - m);
    float sw = wave_sum(e0 + e1 + e2);
    if ((tid & 63) == 0) red[g * 8 + 4 + w4] = sw;
    __syncthreads();
    const float s = red[g * 8 + 4] + red[g * 8 + 5] + red[g * 8 + 6] + red[g * 8 + 7];
    const float inv = 1.f / s;
    buf[st] = e0 * inv;
    buf[st + 256] = e1 * inv;
    buf[st + 512] = e2 * inv;
    __syncthreads();
}

// normalize 2 raw gram rows in LDS: val = G*10/max(ni*nj, eps)
__device__ void norm_rows(float (*buf)[NN], const float* __restrict__ nrm, int i0, int tid) {
    const float n0 = nrm[i0], n1 = nrm[i0 + 1];
    for (int k = tid; k < NN; k += 512) {
        const float nj = nrm[k];
        buf[0][k] = buf[0][k] * 10.f / fmaxf(n0 * nj, CEPS);
        buf[1][k] = buf[1][k] * 10.f / fmaxf(n1 * nj, CEPS);
    }
}

// ---------------- K2: softmax rows -> ve,se (fp32) + hi/lo bf16 splits ----------------
__global__ __launch_bounds__(512) void sm1_kernel(KParams p) {
    __shared__ __align__(16) float ep[2][NN], ex[2][NN];
    __shared__ float red[16];
    const int i0 = blockIdx.x * 2;
    const int tid = threadIdx.x;
    if (tid < 384) {
        ((float4*)ep)[tid] = ((const float4*)(p.simv + (size_t)i0 * NN))[tid];
        ((float4*)ex)[tid] = ((const float4*)(p.sima + (size_t)i0 * NN))[tid];
    }
    __syncthreads();
    norm_rows(ep, p.nrmv, i0, tid);
    norm_rows(ex, p.nrma, i0, tid);
    __syncthreads();
    softmax768_pair(ep[0], ex[0], tid, red);
    softmax768_pair(ep[1], ex[1], tid, red);
    if (tid < 384) {
        ((float4*)(p.ve + (size_t)i0 * NN))[tid] = ((float4*)ep)[tid];
        ((float4*)(p.se + (size_t)i0 * NN))[tid] = ((float4*)ex)[tid];
    }
    #pragma unroll
    for (int j = 0; j < 3; ++j) {
        const int e = tid + j * 512;
        const int row = e / NN, k = e - row * NN;
        const size_t off = (size_t)(i0 + row) * NN + k;
        float v = ep[row][k];
        unsigned short h = f2bf(v);
        p.veh[off] = (short)h;
        p.vel[off] = (short)f2bf(v - __uint_as_float((unsigned)h << 16));
        v = ex[row][k];
        h = f2bf(v);
        p.seh[off] = (short)h;
        p.sel[off] = (short)f2bf(v - __uint_as_float((unsigned)h << 16));
    }
}

// ---------------- agg GEMM: Pagg = (Eh+El)@PT^T, Xagg = (Fh+Fl)@PT^T ----------------
// 12 blocks x 512 thr; waves 0-3 compute Pagg strips, waves 4-7 Xagg. No LDS, no barriers.
__global__ __launch_bounds__(512) void agg_kernel(
        const short* __restrict__ Eh, const short* __restrict__ El,
        const short* __restrict__ Fh, const short* __restrict__ Fl,
        const short* __restrict__ PT, float* __restrict__ Pagg, float* __restrict__ Xagg) {
    const int tid = threadIdx.x, lane = tid & 63, wv = tid >> 6;
    const int grp = wv >> 2, strip = wv & 3;
    const short* Ah = grp ? Fh : Eh;
    const short* Al = grp ? Fl : El;
    float* Out = grp ? Xagg : Pagg;
    const int m = lane & 15, q = lane >> 4;
    const int arow = blockIdx.x * 64 + strip * 16 + m;
    f4v acc[8] = {{0.f, 0.f, 0.f, 0.f}, {0.f, 0.f, 0.f, 0.f}, {0.f, 0.f, 0.f, 0.f},
                  {0.f, 0.f, 0.f, 0.f}, {0.f, 0.f, 0.f, 0.f}, {0.f, 0.f, 0.f, 0.f},
                  {0.f, 0.f, 0.f, 0.f}, {0.f, 0.f, 0.f, 0.f}};
    for (int kb = 0; kb < NN; kb += 32) {
        const s8b ah = *(const s8b*)(Ah + (size_t)arow * NN + kb + q * 8);
        const s8b al = *(const s8b*)(Al + (size_t)arow * NN + kb + q * 8);
        #pragma unroll
        for (int nt = 0; nt < 8; ++nt) {
            const s8b bf = *(const s8b*)(PT + (size_t)(nt * 16 + m) * NN + kb + q * 8);
            acc[nt] = __builtin_amdgcn_mfma_f32_16x16x32_bf16(ah, bf, acc[nt], 0, 0, 0);
            acc[nt] = __builtin_amdgcn_mfma_f32_16x16x32_bf16(al, bf, acc[nt], 0, 0, 0);
        }
    }
    const int orow = blockIdx.x * 64 + strip * 16 + q * 4;
    #pragma unroll
    for (int nt = 0; nt < 8; ++nt) {
        #pragma unroll
        for (int r = 0; r < 4; ++r)
            Out[(size_t)(orow + r) * DD + nt * 16 + m] = acc[nt][r];
    }
}

// ---------------- node tail: qs = p+x, transform, LN, out/outb/cvec (2 rows/block) --------
__global__ __launch_bounds__(512) void tail_kernel(
        const float* __restrict__ Pagg, const float* __restrict__ Xagg,
        const float* __restrict__ WT, const float* __restrict__ b,
        const float* __restrict__ g, const float* __restrict__ beta,
        float* __restrict__ out, const float* __restrict__ W1e,
        short* __restrict__ outb, float* __restrict__ cvec) {
    __shared__ __align__(16) float qs[2][DD], tps[2][2][DD];
    __shared__ float red[16];
    const int i0 = blockIdx.x * 2;
    const int tid = threadIdx.x;
    const int rr = (tid >> 7) & 1, d = tid & 127;
    float preg = 0.f;
    if (tid < 256) {
        const float pv = Pagg[(size_t)(i0 + rr) * DD + d];
        const float xv = Xagg[(size_t)(i0 + rr) * DD + d];
        qs[rr][d] = pv + xv;
        preg = pv;
    }
    __syncthreads();
    {
        const int sc = tid >> 8, rr2 = (tid >> 7) & 1;
        float t = (sc == 0) ? b[d] : 0.f;
        const int c0 = sc * 64;
        #pragma unroll 4
        for (int c = c0; c < c0 + 64; ++c) t = fmaf(qs[rr2][c], WT[(size_t)c * DD + d], t);
        tps[sc][rr2][d] = t;
    }
    __syncthreads();
    float tval = 0.f;
    if (tid < 256) tval = tps[0][rr][d] + tps[1][rr][d];
    float sm = wave_sum(tid < 256 ? tval : 0.f);
    if ((tid & 63) == 0) red[tid >> 6] = sm;
    __syncthreads();
    if (tid < 256) tval -= (red[2 * rr] + red[2 * rr + 1]) * (1.f / DD);
    float s2 = wave_sum(tid < 256 ? tval * tval : 0.f);
    if ((tid & 63) == 0) red[8 + (tid >> 6)] = s2;
    __syncthreads();
    if (tid < 256) {
        const float var = (red[8 + 2 * rr] + red[8 + 2 * rr + 1]) * (1.f / DD);
        const float ln = tval * rsqrtf(var + 1e-5f) * g[d] + beta[d];
        const float val = fmaxf(ln, 0.f) + preg;
        out[(size_t)(i0 + rr) * DD + d] = val;
        outb[(size_t)(i0 + rr) * DD + d] = (short)f2bf(val);
        qs[rr][d] = val;
    }
    __syncthreads();
    if (tid < 256) {
        const int row = tid >> 7, r = (tid >> 4) & 7, l16 = tid & 15;
        float ssum = 0.f;
        #pragma unroll
        for (int t = 0; t < 8; ++t) {
            const int k = l16 + 16 * t;
            const float pv = qs[row][k];
            ssum = fmaf(W1e[r * DD + k], pv * pv, ssum);
        }
        #pragma unroll
        for (int o = 8; o; o >>= 1) ssum += __shfl_down(ssum, o, 16);
        if (l16 == 0) cvec[(size_t)(i0 + row) * HH + r] = ssum;
    }
}

// edge logits into Ls (LDS, unsoftmaxed). Lv = pre-softmaxed last_edge rows.
__device__ void edge_core(const short* __restrict__ PRb, const float* __restrict__ cvec,
                          const float* __restrict__ b1, const float* __restrict__ W2,
                          const float* __restrict__ b2, float invtemp, int i0, int tid,
                          float (*pi)[DD], float* w1s, short* a_sw, float (*Lv)[NN],
                          float (*Ls)[NN]) {
    const int lane = tid & 63, wave = tid >> 6;
    if (tid < 256) {  // A fragments: m = il*8+r, k = t*32 + q2*8 + e
        const int t = tid >> 6, m = lane & 15, q2 = lane >> 4;
        const int il = m >> 3, r = m & 7;
        const int kb = t * 32 + q2 * 8;
        s8b av;
        #pragma unroll
        for (int e = 0; e < 8; ++e)
            av[e] = (short)f2bf(pi[il][kb + e] * w1s[r * DD + kb + e]);
        *(s8b*)&a_sw[(t * 64 + lane) * 8] = av;
    }
    __syncthreads();
    s8b af[4];
    #pragma unroll
    for (int t = 0; t < 4; ++t) af[t] = *(const s8b*)&a_sw[(t * 64 + lane) * 8];
    const int q = lane >> 4, n = lane & 15;
    const int rbase = (q & 1) * 4;
    const int il = q >> 1;
    const float4 ci4 = *(const float4*)&cvec[(size_t)(i0 + il) * HH + rbase];
    const float4 b14 = *(const float4*)&b1[rbase];
    const float4 w24 = *(const float4*)&W2[rbase];
    const float b2s = b2[0];
    #pragma unroll
    for (int s = 0; s < 6; ++s) {
        const int j = wave * 96 + s * 16 + n;
        f4v acc = {0.f, 0.f, 0.f, 0.f};
        #pragma unroll
        for (int t = 0; t < 4; ++t) {
            const s8b bf = *(const s8b*)(PRb + (size_t)j * DD + t * 32 + q * 8);
            acc = __builtin_amdgcn_mfma_f32_16x16x32_bf16(af[t], bf, acc, 0, 0, 0);
        }
        const float4 cj = *(const float4*)&cvec[(size_t)j * HH + rbase];
        float z[4];
        z[0] = ci4.x + cj.x - 2.f * acc[0] + b14.x;
        z[1] = ci4.y + cj.y - 2.f * acc[1] + b14.y;
        z[2] = ci4.z + cj.z - 2.f * acc[2] + b14.z;
        z[3] = ci4.w + cj.w - 2.f * acc[3] + b14.w;
        float s1 = z[0] + z[1] + z[2] + z[3];
        float s2 = z[0] * z[0] + z[1] * z[1] + z[2] * z[2] + z[3] * z[3];
        s1 += __shfl_xor(s1, 16, 64);
        s2 += __shfl_xor(s2, 16, 64);
        const float mean = s1 * (1.f / HH);
        const float var = fmaxf(s2 * (1.f / HH) - mean * mean, 0.f);
        const float istd = rsqrtf(var + 1e-5f);
        float a2 = 0.f;
        a2 = fmaf(fmaxf((z[0] - mean) * istd, 0.f), w24.x, a2);
        a2 = fmaf(fmaxf((z[1] - mean) * istd, 0.f), w24.y, a2);
        a2 = fmaf(fmaxf((z[2] - mean) * istd, 0.f), w24.z, a2);
        a2 = fmaf(fmaxf((z[3] - mean) * istd, 0.f), w24.w, a2);
        a2 += __shfl_xor(a2, 16, 64);
        const float tv = tanhf(a2 + b2s);
        const float lv = Lv[il][j];
        if ((q & 1) == 0) Ls[il][j] = tv * (lv + CEPS) * invtemp;
    }
    __syncthreads();
}

// ---------------- edge1: logits + softmax -> ve2 (fp32) + hi/lo splits ----------------
__global__ __launch_bounds__(512) void edge1_kernel(KParams p) {
    __shared__ __align__(16) float pi[2][DD];
    __shared__ __align__(16) float w1s[HH * DD];
    __shared__ __align__(16) short a_sw[4 * 64 * 8];
    __shared__ __align__(16) float Lv[2][NN];
    __shared__ __align__(16) float Ls[2][NN];
    __shared__ float red[16];
    const int i0 = blockIdx.x * 2;
    const int tid = threadIdx.x;
    if (tid < 256) {
        pi[tid >> 7][tid & 127] = p.vp[(size_t)(i0 + (tid >> 7)) * DD + (tid & 127)];
        ((float4*)w1s)[tid] = ((const float4*)p.Wve1)[tid];
    }
    if (tid < 384)
        ((float4*)Lv)[tid] = ((const float4*)(p.ve + (size_t)i0 * NN))[tid];
    __syncthreads();
    edge_core(p.vpb, p.cvec1, p.bve1, p.Wve2, p.bve2, 0.1f, i0, tid, pi, w1s, a_sw, Lv, Ls);
    softmax768_pair(Ls[0], Ls[1], tid, red);
    if (tid < 384)
        ((float4*)(p.ve2 + (size_t)i0 * NN))[tid] = ((float4*)Ls)[tid];
    #pragma unroll
    for (int j = 0; j < 3; ++j) {
        const int e = tid + j * 512;
        const int row = e / NN, k = e - row * NN;
        const size_t off = (size_t)(i0 + row) * NN + k;
        const float v = Ls[row][k];
        const unsigned short h = f2bf(v);
        p.ve2h[off] = (short)h;
        p.ve2l[off] = (short)f2bf(v - __uint_as_float((unsigned)h << 16));
    }
}

// ---------------- edge2 (2 rows/block, 512 thr) ----------------
__global__ __launch_bounds__(512) void edge2_kernel(KParams p) {
    __shared__ __align__(16) float pi[2][DD];
    __shared__ __align__(16) float w1s[HH * DD];
    __shared__ __align__(16) short a_sw[4 * 64 * 8];
    __shared__ __align__(16) float Lv[2][NN];
    __shared__ __align__(16) float Ls[2][NN];
    __shared__ float red[16];
    const int i0 = blockIdx.x * 2;
    const int tid = threadIdx.x;
    if (tid < 256) {
        pi[tid >> 7][tid & 127] = p.sp[(size_t)(i0 + (tid >> 7)) * DD + (tid & 127)];
        ((float4*)w1s)[tid] = ((const float4*)p.Wse1)[tid];
    }
    if (tid < 384)
        ((float4*)Lv)[tid] = ((const float4*)(p.se + (size_t)i0 * NN))[tid];
    __syncthreads();
    edge_core(p.spb, p.cvec2, p.bse1, p.Wse2, p.bse2, 0.1f, i0, tid, pi, w1s, a_sw, Lv, Ls);
    softmax768_pair(Ls[0], Ls[1], tid, red);
    float* d0 = p.se2 + (size_t)i0 * NN;
    float* d1 = p.se2 + (size_t)(i0 + 1) * NN;
    d0[tid] = Ls[0][tid];
    d1[tid] = Ls[1][tid];
    if (tid < NN - 512) {
        d0[tid + 512] = Ls[0][tid + 512];
        d1[tid + 512] = Ls[1][tid + 512];
    }
}

extern "C" void kernel_launch(void* const* d_in, const int* in_sizes, int n_in, void* d_out,
                              int out_size, void* d_ws, size_t ws_size, hipStream_t stream) {
    KParams kp;
    kp.visual    = (const float*)d_in[0];
    kp.semantic  = (const float*)d_in[1];
    kp.attribute = (const float*)d_in[2];
    kp.Wvn  = (const float*)d_in[3];
    kp.bvn  = (const float*)d_in[4];
    kp.gvn  = (const float*)d_in[5];
    kp.betavn = (const float*)d_in[6];
    kp.Wve1 = (const float*)d_in[7];
    kp.bve1 = (const float*)d_in[8];
    kp.Wve2 = (const float*)d_in[9];
    kp.bve2 = (const float*)d_in[10];
    kp.Wsn  = (const float*)d_in[11];
    kp.bsn  = (const float*)d_in[12];
    kp.gsn  = (const float*)d_in[13];
    kp.betasn = (const float*)d_in[14];
    kp.Wse1 = (const float*)d_in[15];
    kp.bse1 = (const float*)d_in[16];
    kp.Wse2 = (const float*)d_in[17];
    kp.bse2 = (const float*)d_in[18];

    float* out = (float*)d_out;
    kp.vp  = out;              // 768*128
    kp.sp  = out + 98304;      // 768*128
    kp.ve2 = out + 196608;     // 768*768
    kp.se2 = out + 786432;     // 768*768

    float* ws = (float*)d_ws;
    kp.simv  = ws;             // 768*768 RAW gram
    kp.sima  = ws + 589824;
    kp.ve    = ws + 1179648;   // softmax(norm(simv))
    kp.se    = ws + 1769472;   // softmax(norm(sima))
    kp.pagg1 = ws + 2359296;   // 768*128
    kp.xagg1 = ws + 2457600;
    kp.pagg2 = ws + 2555904;
    kp.xagg2 = ws + 2654208;
    kp.WvnT  = ws + 2949120;   // 128*128
    kp.WsnT  = ws + 2965504;
    kp.cvec1 = ws + 2981888;   // 768*8
    kp.cvec2 = ws + 2988032;
    kp.vpb   = (short*)(ws + 2994176);  // 768*128 bf16
    kp.spb   = (short*)(ws + 3043328);
    kp.nrmv  = ws + 3092480;   // 768
    kp.nrma  = ws + 3093248;
    kp.visbT = (short*)(ws + 3094016);  // [128][768] bf16
    kp.sembT = (short*)(ws + 3143168);
    kp.veh   = (short*)(ws + 3192320);  // 768*768 bf16 each
    kp.vel   = (short*)(ws + 3487232);
    kp.seh   = (short*)(ws + 3782144);
    kp.sel   = (short*)(ws + 4077056);
    kp.ve2h  = (short*)(ws + 4371968);
    kp.ve2l  = (short*)(ws + 4666880);

    gram_mfma_kernel<<<344, 256, 0, stream>>>(kp);
    sm1_kernel<<<NN / 2, 512, 0, stream>>>(kp);
    agg_kernel<<<12, 512, 0, stream>>>(kp.veh, kp.vel, kp.seh, kp.sel, kp.visbT, kp.pagg1,
                                       kp.xagg1);
    tail_kernel<<<NN / 2, 512, 0, stream>>>(kp.pagg1, kp.xagg1, kp.WvnT, kp.bvn, kp.gvn,
                                            kp.betavn, kp.vp, kp.Wve1, kp.vpb, kp.cvec1);
    edge1_kernel<<<NN / 2, 512, 0, stream>>>(kp);
    agg_kernel<<<12, 512, 0, stream>>>(kp.seh, kp.sel, kp.ve2h, kp.ve2l, kp.sembT, kp.pagg2,
                                       kp.xagg2);
    tail_kernel<<<NN / 2, 512, 0, stream>>>(kp.pagg2, kp.xagg2, kp.WsnT, kp.bsn, kp.gsn,
                                            kp.betasn, kp.sp, kp.Wse1, kp.spb, kp.cvec2);
    edge2_kernel<<<NN / 2, 512, 0, stream>>>(kp);
}

// Round 13
// 168.382 us; speedup vs baseline: 1.7286x; 1.7286x over previous
//
#include <hip/hip_runtime.h>
#include <math.h>

#define NN 768
#define DD 128
#define AA 312
#define HH 8
#define CEPS 1e-8f

typedef __attribute__((ext_vector_type(8))) short s8b;   // 8 x bf16
typedef __attribute__((ext_vector_type(4))) float f4v;   // MFMA C/D

__device__ __forceinline__ float wave_sum(float v) {
    #pragma unroll
    for (int o = 32; o; o >>= 1) v += __shfl_down(v, o, 64);
    return v;
}
__device__ __forceinline__ float wave_max(float v) {
    #pragma unroll
    for (int o = 32; o; o >>= 1) v = fmaxf(v, __shfl_down(v, o, 64));
    return v;
}
__device__ __forceinline__ unsigned short f2bf(float f) {
    unsigned u = __float_as_uint(f);
    u += 0x7FFFu + ((u >> 16) & 1u);
    return (unsigned short)(u >> 16);
}

struct KParams {
    const float *visual, *semantic, *attribute;
    const float *Wvn, *bvn, *gvn, *betavn, *Wve1, *bve1, *Wve2, *bve2;
    const float *Wsn, *bsn, *gsn, *betasn, *Wse1, *bse1, *Wse2, *bse2;
    float *vp, *sp, *ve2, *se2;
    float *simv, *sima, *WvnT, *WsnT, *cvec1, *cvec2;
    float *nrmv, *nrma, *ve, *se;
    short *vpb, *spb, *visb, *semb;
};

// ---------------- K1: MFMA bf16x2-split gram + diag norms + W transposes + bf16 copies -----
__global__ __launch_bounds__(256) void gram_mfma_kernel(KParams p) {
    __shared__ __align__(16) unsigned short AH[64 * 40];
    __shared__ __align__(16) unsigned short AL[64 * 40];
    __shared__ __align__(16) unsigned short BH[64 * 40];
    __shared__ __align__(16) unsigned short BL[64 * 40];
    const int task = blockIdx.x;
    const int tid = threadIdx.x;
    if (task < 288) {
        const bool isv = (task < 144);
        const int tt = isv ? task : task - 144;
        const int bi = tt / 12, bj = tt % 12;
        const float* M = isv ? p.visual : p.attribute;
        float* G = isv ? p.simv : p.sima;
        float* nrm = isv ? p.nrmv : p.nrma;
        const int K = isv ? DD : AA;
        const int i0 = bi * 64, j0 = bj * 64;
        const int w = tid >> 6, lane = tid & 63;
        const int m = lane & 15, q = lane >> 4;
        f4v acc[4] = {{0.f, 0.f, 0.f, 0.f}, {0.f, 0.f, 0.f, 0.f},
                      {0.f, 0.f, 0.f, 0.f}, {0.f, 0.f, 0.f, 0.f}};
        const int nchunk = (K + 31) >> 5;
        const int srow = tid >> 2, sq = (tid & 3) * 8;
        for (int c = 0; c < nchunk; ++c) {
            const int kc = c * 32;
            __syncthreads();
            #pragma unroll
            for (int h = 0; h < 2; ++h) {
                const int col = sq + h * 4;
                float4 a = {0.f, 0.f, 0.f, 0.f}, b = {0.f, 0.f, 0.f, 0.f};
                if (kc + col + 4 <= K) {
                    a = *(const float4*)(M + (size_t)(i0 + srow) * K + kc + col);
                    b = *(const float4*)(M + (size_t)(j0 + srow) * K + kc + col);
                }
                const float av[4] = {a.x, a.y, a.z, a.w};
                const float bv[4] = {b.x, b.y, b.z, b.w};
                #pragma unroll
                for (int e = 0; e < 4; ++e) {
                    const unsigned short ah = f2bf(av[e]);
                    const float ahf = __uint_as_float((unsigned)ah << 16);
                    const unsigned short al = f2bf(av[e] - ahf);
                    const unsigned short bh = f2bf(bv[e]);
                    const float bhf = __uint_as_float((unsigned)bh << 16);
                    const unsigned short bl = f2bf(bv[e] - bhf);
                    AH[srow * 40 + col + e] = ah;
                    AL[srow * 40 + col + e] = al;
                    BH[srow * 40 + col + e] = bh;
                    BL[srow * 40 + col + e] = bl;
                }
            }
            __syncthreads();
            const s8b ah8 = *(const s8b*)&AH[(w * 16 + m) * 40 + q * 8];
            const s8b al8 = *(const s8b*)&AL[(w * 16 + m) * 40 + q * 8];
            #pragma unroll
            for (int jt = 0; jt < 4; ++jt) {
                const s8b bh8 = *(const s8b*)&BH[(jt * 16 + m) * 40 + q * 8];
                const s8b bl8 = *(const s8b*)&BL[(jt * 16 + m) * 40 + q * 8];
                acc[jt] = __builtin_amdgcn_mfma_f32_16x16x32_bf16(ah8, bh8, acc[jt], 0, 0, 0);
                acc[jt] = __builtin_amdgcn_mfma_f32_16x16x32_bf16(ah8, bl8, acc[jt], 0, 0, 0);
                acc[jt] = __builtin_amdgcn_mfma_f32_16x16x32_bf16(al8, bh8, acc[jt], 0, 0, 0);
            }
        }
        #pragma unroll
        for (int jt = 0; jt < 4; ++jt) {
            #pragma unroll
            for (int r = 0; r < 4; ++r) {
                G[(size_t)(i0 + w * 16 + q * 4 + r) * NN + j0 + jt * 16 + m] = acc[jt][r];
                if (bi == bj && jt == w && m == q * 4 + r)
                    nrm[i0 + w * 16 + m] = sqrtf(fmaxf(acc[jt][r], 0.f));
            }
        }
    } else if (task < 320) {
        float* smem = (float*)AH;
        const int u = task - 288;
        const float* S = (u >= 16) ? p.Wsn : p.Wvn;
        float* Dt = (u >= 16) ? p.WsnT : p.WvnT;
        const int tile = u & 15;
        const int c0 = (tile & 3) * 32, r0 = (tile >> 2) * 32;
        const int tx = tid & 31, ty = tid >> 5;
        #pragma unroll
        for (int rr = ty; rr < 32; rr += 8)
            smem[rr * 33 + tx] = S[(size_t)(r0 + rr) * DD + c0 + tx];
        __syncthreads();
        #pragma unroll
        for (int rr = ty; rr < 32; rr += 8)
            Dt[(size_t)(c0 + rr) * DD + r0 + tx] = smem[tx * 33 + rr];
    } else {
        // bf16 copies of visual (tasks 320-331) / semantic (tasks 332-343); 8192 elems/block
        const int u = task - 320;
        const bool isv = (u < 12);
        const float* src = isv ? p.visual : p.semantic;
        short* dst = isv ? p.visb : p.semb;
        const int base = (isv ? u : u - 12) * 8192;
        for (int e = tid * 4; e < 8192; e += 1024) {
            const float4 v = *(const float4*)(src + base + e);
            const unsigned lo = (unsigned)f2bf(v.x) | ((unsigned)f2bf(v.y) << 16);
            const unsigned hi = (unsigned)f2bf(v.z) | ((unsigned)f2bf(v.w) << 16);
            *(uint2*)(dst + base + e) = make_uint2(lo, hi);
        }
    }
}

// Two concurrent 768-float softmaxes: waves 0-3 on A, waves 4-7 on B. 3 barriers.
__device__ void softmax768_pair(float* A, float* B, int tid, float* red) {
    float* buf = (tid < 256) ? A : B;
    const int st = tid & 255;
    const int g = tid >> 8;
    const int w4 = (tid >> 6) & 3;
    float v0 = buf[st], v1 = buf[st + 256], v2 = buf[st + 512];
    float m = wave_max(fmaxf(fmaxf(v0, v1), v2));
    if ((tid & 63) == 0) red[g * 8 + w4] = m;
    __syncthreads();
    m = fmaxf(fmaxf(red[g * 8], red[g * 8 + 1]), fmaxf(red[g * 8 + 2], red[g * 8 + 3]));
    float e0 = __expf(v0 - m), e1 = __expf(v1 - m), e2 = __expf(v2 - m);
    float sw = wave_sum(e0 + e1 + e2);
    if ((tid & 63) == 0) red[g * 8 + 4 + w4] = sw;
    __syncthreads();
    const float s = red[g * 8 + 4] + red[g * 8 + 5] + red[g * 8 + 6] + red[g * 8 + 7];
    const float inv = 1.f / s;
    buf[st] = e0 * inv;
    buf[st + 256] = e1 * inv;
    buf[st + 512] = e2 * inv;
    __syncthreads();
}

// normalize 2 raw gram rows in LDS: val = G*10/max(ni*nj, eps). Thread t owns {t, t+512}.
__device__ void norm_rows(float (*buf)[NN], const float* __restrict__ nrm, int i0, int tid) {
    const float n0 = nrm[i0], n1 = nrm[i0 + 1];
    for (int k = tid; k < NN; k += 512) {
        const float nj = nrm[k];
        buf[0][k] = buf[0][k] * 10.f / fmaxf(n0 * nj, CEPS);
        buf[1][k] = buf[1][k] * 10.f / fmaxf(n1 * nj, CEPS);
    }
}

// node tail. ep/ex: softmaxed rows in LDS. Pb: bf16 P matrix [768][128].
__device__ void node_core(const short* __restrict__ Pb, float (*ep)[NN], float (*ex)[NN],
                          const float* __restrict__ WT, const float* __restrict__ b,
                          const float* __restrict__ g, const float* __restrict__ beta,
                          float* __restrict__ out, const float* __restrict__ W1e,
                          short* __restrict__ outb, float* __restrict__ cvec, int i0, int tid,
                          float* ppart, float* xpart, float (*qs)[DD], float (*tps)[2][DD],
                          float* red) {
    // aggregation: 8 k-groups (one per wave) x 64 d-pairs; bf16-pair P loads.
    {
        const int kg = tid >> 6, dp = tid & 63, d0 = dp * 2;
        const unsigned* Pb2 = (const unsigned*)Pb;
        float a00 = 0.f, a01 = 0.f, a10 = 0.f, a11 = 0.f;
        float b00 = 0.f, b01 = 0.f, b10 = 0.f, b11 = 0.f;
        const int kb = kg * 96;
        #pragma unroll 8
        for (int i = 0; i < 96; ++i) {
            const int k = kb + i;
            const unsigned pvu = Pb2[(size_t)k * 64 + dp];
            const float pvx = __uint_as_float(pvu << 16);
            const float pvy = __uint_as_float(pvu & 0xffff0000u);
            const float e0 = ep[0][k], e1 = ep[1][k];
            const float f0 = ex[0][k], f1 = ex[1][k];
            a00 = fmaf(e0, pvx, a00); a01 = fmaf(e0, pvy, a01);
            a10 = fmaf(e1, pvx, a10); a11 = fmaf(e1, pvy, a11);
            b00 = fmaf(f0, pvx, b00); b01 = fmaf(f0, pvy, b01);
            b10 = fmaf(f1, pvx, b10); b11 = fmaf(f1, pvy, b11);
        }
        float* pp = ppart + kg * 260;  // [2][130] slab, stride 260 == 4 (mod 32) banks
        float* xp = xpart + kg * 260;
        pp[d0] = a00; pp[d0 + 1] = a01; pp[130 + d0] = a10; pp[130 + d0 + 1] = a11;
        xp[d0] = b00; xp[d0 + 1] = b01; xp[130 + d0] = b10; xp[130 + d0 + 1] = b11;
    }
    __syncthreads();
    const int rr = (tid >> 7) & 1, d = tid & 127;
    float preg = 0.f;
    if (tid < 256) {
        float p = 0.f, x = 0.f;
        #pragma unroll
        for (int kk = 0; kk < 8; ++kk) {
            p += ppart[kk * 260 + rr * 130 + d];
            x += xpart[kk * 260 + rr * 130 + d];
        }
        qs[rr][d] = p + x;
        preg = p;
    }
    __syncthreads();
    {
        const int sc = tid >> 8, rr2 = (tid >> 7) & 1;
        float t = (sc == 0) ? b[d] : 0.f;
        const int c0 = sc * 64;
        #pragma unroll 4
        for (int c = c0; c < c0 + 64; ++c) t = fmaf(qs[rr2][c], WT[(size_t)c * DD + d], t);
        tps[sc][rr2][d] = t;
    }
    __syncthreads();
    float tval = 0.f;
    if (tid < 256) tval = tps[0][rr][d] + tps[1][rr][d];
    float sm = wave_sum(tid < 256 ? tval : 0.f);
    if ((tid & 63) == 0) red[tid >> 6] = sm;
    __syncthreads();
    if (tid < 256) tval -= (red[2 * rr] + red[2 * rr + 1]) * (1.f / DD);
    float s2 = wave_sum(tid < 256 ? tval * tval : 0.f);
    if ((tid & 63) == 0) red[8 + (tid >> 6)] = s2;
    __syncthreads();
    if (tid < 256) {
        const float var = (red[8 + 2 * rr] + red[8 + 2 * rr + 1]) * (1.f / DD);
        const float ln = tval * rsqrtf(var + 1e-5f) * g[d] + beta[d];
        const float val = fmaxf(ln, 0.f) + preg;
        out[(size_t)(i0 + rr) * DD + d] = val;
        outb[(size_t)(i0 + rr) * DD + d] = (short)f2bf(val);
        qs[rr][d] = val;
    }
    __syncthreads();
    if (tid < 256) {
        const int row = tid >> 7, r = (tid >> 4) & 7, l16 = tid & 15;
        float ssum = 0.f;
        #pragma unroll
        for (int t = 0; t < 8; ++t) {
            const int k = l16 + 16 * t;
            const float pv = qs[row][k];
            ssum = fmaf(W1e[r * DD + k], pv * pv, ssum);
        }
        #pragma unroll
        for (int o = 8; o; o >>= 1) ssum += __shfl_down(ssum, o, 16);
        if (l16 == 0) cvec[(size_t)(i0 + row) * HH + r] = ssum;
    }
}

// ---------------- K2: node1 (2 rows/block, 512 thr) ----------------
__global__ __launch_bounds__(512) void node1_kernel(KParams p) {
    __shared__ __align__(16) float ep[2][NN], ex[2][NN];
    __shared__ __align__(16) float ppart[8 * 260], xpart[8 * 260];
    __shared__ __align__(16) float qs[2][DD], tps[2][2][DD];
    __shared__ float red[16];
    const int i0 = blockIdx.x * 2;
    const int tid = threadIdx.x;
    if (tid < 384) {
        ((float4*)ep)[tid] = ((const float4*)(p.simv + (size_t)i0 * NN))[tid];
        ((float4*)ex)[tid] = ((const float4*)(p.sima + (size_t)i0 * NN))[tid];
    }
    __syncthreads();
    norm_rows(ep, p.nrmv, i0, tid);
    norm_rows(ex, p.nrma, i0, tid);
    __syncthreads();
    softmax768_pair(ep[0], ex[0], tid, red);
    softmax768_pair(ep[1], ex[1], tid, red);
    if (tid < 384) {  // materialize ve/se rows for downstream kernels
        ((float4*)(p.ve + (size_t)i0 * NN))[tid] = ((float4*)ep)[tid];
        ((float4*)(p.se + (size_t)i0 * NN))[tid] = ((float4*)ex)[tid];
    }
    node_core(p.visb, ep, ex, p.WvnT, p.bvn, p.gvn, p.betavn, p.vp, p.Wve1, p.vpb, p.cvec1,
              i0, tid, ppart, xpart, qs, tps, red);
}

// edge logits into Ls (LDS, unsoftmaxed). Lv = pre-softmaxed last_edge rows.
__device__ void edge_core(const short* __restrict__ PRb, const float* __restrict__ cvec,
                          const float* __restrict__ W1, const float* __restrict__ b1,
                          const float* __restrict__ W2, const float* __restrict__ b2,
                          float invtemp, int i0, int tid, float (*pi)[DD], float* w1s,
                          short* a_sw, float (*Lv)[NN], float (*Ls)[NN]) {
    const int lane = tid & 63, wave = tid >> 6;
    if (tid < 256) {  // A fragments: m = il*8+r, k = t*32 + q2*8 + e
        const int t = tid >> 6, m = lane & 15, q2 = lane >> 4;
        const int il = m >> 3, r = m & 7;
        const int kb = t * 32 + q2 * 8;
        s8b av;
        #pragma unroll
        for (int e = 0; e < 8; ++e)
            av[e] = (short)f2bf(pi[il][kb + e] * w1s[r * DD + kb + e]);
        *(s8b*)&a_sw[(t * 64 + lane) * 8] = av;
    }
    __syncthreads();
    s8b af[4];
    #pragma unroll
    for (int t = 0; t < 4; ++t) af[t] = *(const s8b*)&a_sw[(t * 64 + lane) * 8];
    const int q = lane >> 4, n = lane & 15;
    const int rbase = (q & 1) * 4;
    const int il = q >> 1;
    const float4 ci4 = *(const float4*)&cvec[(size_t)(i0 + il) * HH + rbase];
    const float4 b14 = *(const float4*)&b1[rbase];
    const float4 w24 = *(const float4*)&W2[rbase];
    const float b2s = b2[0];
    #pragma unroll
    for (int s = 0; s < 6; ++s) {
        const int j = wave * 96 + s * 16 + n;
        f4v acc = {0.f, 0.f, 0.f, 0.f};
        #pragma unroll
        for (int t = 0; t < 4; ++t) {
            const s8b bf = *(const s8b*)(PRb + (size_t)j * DD + t * 32 + q * 8);
            acc = __builtin_amdgcn_mfma_f32_16x16x32_bf16(af[t], bf, acc, 0, 0, 0);
        }
        const float4 cj = *(const float4*)&cvec[(size_t)j * HH + rbase];
        float z[4];
        z[0] = ci4.x + cj.x - 2.f * acc[0] + b14.x;
        z[1] = ci4.y + cj.y - 2.f * acc[1] + b14.y;
        z[2] = ci4.z + cj.z - 2.f * acc[2] + b14.z;
        z[3] = ci4.w + cj.w - 2.f * acc[3] + b14.w;
        float s1 = z[0] + z[1] + z[2] + z[3];
        float s2 = z[0] * z[0] + z[1] * z[1] + z[2] * z[2] + z[3] * z[3];
        s1 += __shfl_xor(s1, 16, 64);
        s2 += __shfl_xor(s2, 16, 64);
        const float mean = s1 * (1.f / HH);
        const float var = fmaxf(s2 * (1.f / HH) - mean * mean, 0.f);
        const float istd = rsqrtf(var + 1e-5f);
        float a2 = 0.f;
        a2 = fmaf(fmaxf((z[0] - mean) * istd, 0.f), w24.x, a2);
        a2 = fmaf(fmaxf((z[1] - mean) * istd, 0.f), w24.y, a2);
        a2 = fmaf(fmaxf((z[2] - mean) * istd, 0.f), w24.z, a2);
        a2 = fmaf(fmaxf((z[3] - mean) * istd, 0.f), w24.w, a2);
        a2 += __shfl_xor(a2, 16, 64);
        const float tv = tanhf(a2 + b2s);
        const float lv = Lv[il][j];
        if ((q & 1) == 0) Ls[il][j] = tv * (lv + CEPS) * invtemp;
    }
    __syncthreads();
}

// ---------------- K3: edge1 + node2 fused (2 rows/block, 512 thr) ----------------
__global__ __launch_bounds__(512) void edge_node_kernel(KParams p) {
    __shared__ __align__(16) float pi[2][DD];
    __shared__ __align__(16) float w1s[HH * DD];
    __shared__ __align__(16) short a_sw[4 * 64 * 8];
    __shared__ __align__(16) float Lv[2][NN];
    __shared__ __align__(16) float Ls[2][NN];
    __shared__ __align__(16) float ep[2][NN];
    __shared__ __align__(16) float ppart[8 * 260], xpart[8 * 260];
    __shared__ __align__(16) float qs[2][DD], tps[2][2][DD];
    __shared__ float red[16];
    const int i0 = blockIdx.x * 2;
    const int tid = threadIdx.x;
    if (tid < 256) {
        pi[tid >> 7][tid & 127] = p.vp[(size_t)(i0 + (tid >> 7)) * DD + (tid & 127)];
        ((float4*)w1s)[tid] = ((const float4*)p.Wve1)[tid];
    }
    if (tid < 384) {
        ((float4*)Lv)[tid] = ((const float4*)(p.ve + (size_t)i0 * NN))[tid];
        ((float4*)ep)[tid] = ((const float4*)(p.se + (size_t)i0 * NN))[tid];
    }
    __syncthreads();
    edge_core(p.vpb, p.cvec1, p.Wve1, p.bve1, p.Wve2, p.bve2, 0.1f, i0, tid, pi, w1s, a_sw,
              Lv, Ls);
    softmax768_pair(Ls[0], Ls[1], tid, red);
    if (tid < 384)  // write ve2 rows
        ((float4*)(p.ve2 + (size_t)i0 * NN))[tid] = ((float4*)Ls)[tid];
    // node2: ep = se rows (pre-softmaxed), ex = Ls (= ve2 rows, in LDS)
    node_core(p.semb, ep, Ls, p.WsnT, p.bsn, p.gsn, p.betasn, p.sp, p.Wse1, p.spb,
              p.cvec2, i0, tid, ppart, xpart, qs, tps, red);
}

// ---------------- K4: edge2 (2 rows/block, 512 thr) ----------------
__global__ __launch_bounds__(512) void edge2_kernel(KParams p) {
    __shared__ __align__(16) float pi[2][DD];
    __shared__ __align__(16) float w1s[HH * DD];
    __shared__ __align__(16) short a_sw[4 * 64 * 8];
    __shared__ __align__(16) float Lv[2][NN];
    __shared__ __align__(16) float Ls[2][NN];
    __shared__ float red[16];
    const int i0 = blockIdx.x * 2;
    const int tid = threadIdx.x;
    if (tid < 256) {
        pi[tid >> 7][tid & 127] = p.sp[(size_t)(i0 + (tid >> 7)) * DD + (tid & 127)];
        ((float4*)w1s)[tid] = ((const float4*)p.Wse1)[tid];
    }
    if (tid < 384)
        ((float4*)Lv)[tid] = ((const float4*)(p.se + (size_t)i0 * NN))[tid];
    __syncthreads();
    edge_core(p.spb, p.cvec2, p.Wse1, p.bse1, p.Wse2, p.bse2, 0.1f, i0, tid, pi, w1s, a_sw,
              Lv, Ls);
    softmax768_pair(Ls[0], Ls[1], tid, red);
    float* d0 = p.se2 + (size_t)i0 * NN;
    float* d1 = p.se2 + (size_t)(i0 + 1) * NN;
    d0[tid] = Ls[0][tid];
    d1[tid] = Ls[1][tid];
    if (tid < NN - 512) {
        d0[tid + 512] = Ls[0][tid + 512];
        d1[tid + 512] = Ls[1][tid + 512];
    }
}

extern "C" void kernel_launch(void* const* d_in, const int* in_sizes, int n_in, void* d_out,
                              int out_size, void* d_ws, size_t ws_size, hipStream_t stream) {
    KParams kp;
    kp.visual    = (const float*)d_in[0];
    kp.semantic  = (const float*)d_in[1];
    kp.attribute = (const float*)d_in[2];
    kp.Wvn  = (const float*)d_in[3];
    kp.bvn  = (const float*)d_in[4];
    kp.gvn  = (const float*)d_in[5];
    kp.betavn = (const float*)d_in[6];
    kp.Wve1 = (const float*)d_in[7];
    kp.bve1 = (const float*)d_in[8];
    kp.Wve2 = (const float*)d_in[9];
    kp.bve2 = (const float*)d_in[10];
    kp.Wsn  = (const float*)d_in[11];
    kp.bsn  = (const float*)d_in[12];
    kp.gsn  = (const float*)d_in[13];
    kp.betasn = (const float*)d_in[14];
    kp.Wse1 = (const float*)d_in[15];
    kp.bse1 = (const float*)d_in[16];
    kp.Wse2 = (const float*)d_in[17];
    kp.bse2 = (const float*)d_in[18];

    float* out = (float*)d_out;
    kp.vp  = out;              // 768*128
    kp.sp  = out + 98304;      // 768*128
    kp.ve2 = out + 196608;     // 768*768
    kp.se2 = out + 786432;     // 768*768

    float* ws = (float*)d_ws;
    kp.simv  = ws;             // 768*768 RAW gram
    kp.sima  = ws + 589824;
    kp.ve    = ws + 1179648;   // materialized softmax(norm(simv))
    kp.se    = ws + 1769472;   // materialized softmax(norm(sima))
    kp.WvnT  = ws + 2949120;   // 128*128
    kp.WsnT  = ws + 2965504;
    kp.cvec1 = ws + 2981888;   // 768*8
    kp.cvec2 = ws + 2988032;
    kp.vpb   = (short*)(ws + 2994176);  // 768*128 bf16 (49152 floats)
    kp.spb   = (short*)(ws + 3043328);
    kp.nrmv  = ws + 3092480;   // 768
    kp.nrma  = ws + 3093248;
    kp.visb  = (short*)(ws + 3094016);  // 768*128 bf16 copy of visual
    kp.semb  = (short*)(ws + 3143168);  // 768*128 bf16 copy of semantic

    gram_mfma_kernel<<<344, 256, 0, stream>>>(kp);
    node1_kernel<<<NN / 2, 512, 0, stream>>>(kp);
    edge_node_kernel<<<NN / 2, 512, 0, stream>>>(kp);
    edge2_kernel<<<NN / 2, 512, 0, stream>>>(kp);
}